// Round 6
// baseline (213.850 us; speedup 1.0000x reference)
//
#include <hip/hip_runtime.h>
#include <stdint.h>

#define V 128000
#define BROWS 256
#define SEGS 8
#define SEGLEN (V / SEGS)      // 16000
#define SEG4 (SEGLEN / 4)      // 4000
#define CAPSEG 512             // per-segment candidate cap (expect ~22)
#define CAPB 4096              // gather/slow-path cap
#define NT_A 256
#define NT_B 256
#define T0 16.0f

typedef unsigned long long u64;

__device__ __forceinline__ unsigned rotl32(unsigned x, int d) {
  return (x << d) | (x >> (32 - d));
}

// JAX threefry2x32, key (0,42). Partitionable path: counter=(0,i);
// 32-bit draw = XOR-fold of the two output words. [verified: R4/R5 passed]
__device__ __forceinline__ uint2 threefry2x32(unsigned x0, unsigned x1) {
  const unsigned k0 = 0u, k1 = 42u;
  const unsigned k2 = k0 ^ k1 ^ 0x1BD11BDAu;
  x0 += k0; x1 += k1;
#define TF_RND(r) { x0 += x1; x1 = rotl32(x1, r); x1 ^= x0; }
  TF_RND(13) TF_RND(15) TF_RND(26) TF_RND(6)
  x0 += k1; x1 += k2 + 1u;
  TF_RND(17) TF_RND(29) TF_RND(16) TF_RND(24)
  x0 += k2; x1 += k0 + 2u;
  TF_RND(13) TF_RND(15) TF_RND(26) TF_RND(6)
  x0 += k0; x1 += k1 + 3u;
  TF_RND(17) TF_RND(29) TF_RND(16) TF_RND(24)
  x0 += k1; x1 += k2 + 4u;
  TF_RND(13) TF_RND(15) TF_RND(26) TF_RND(6)
  x0 += k2; x1 += k0 + 5u;
#undef TF_RND
  return make_uint2(x0, x1);
}

__device__ __forceinline__ float gumbel_at(unsigned flat) {
  uint2 r = threefry2x32(0u, flat);
  unsigned bits = r.x ^ r.y;  // XOR fold
  float f = __uint_as_float((bits >> 9) | 0x3F800000u) - 1.0f;
  const float TINY = 1.17549435e-38f;
  float u = fmaxf(TINY, f + TINY);
  return -logf(-logf(u));
}

// monotone float -> uint (total order)
__device__ __forceinline__ unsigned fkey(float v) {
  unsigned u = __float_as_uint(v);
  return (u & 0x80000000u) ? ~u : (u | 0x80000000u);
}
__device__ __forceinline__ float fkey_inv(unsigned u) {
  unsigned r = (u & 0x80000000u) ? (u & 0x7FFFFFFFu) : ~u;
  return __uint_as_float(r);
}

// ---------------- Kernel A: per-segment scan (grid = BROWS*SEGS) -------------
extern "C" __global__ void __launch_bounds__(NT_A)
scan_seg_kernel(const float* __restrict__ logits,
                int* __restrict__ g_cnt, float* __restrict__ g_z,
                u64* __restrict__ g_cand) {
  const int bid = blockIdx.x;
  const int row = bid >> 3, seg = bid & 7;
  const int tid = threadIdx.x;

  __shared__ u64 lcand[CAPSEG];
  __shared__ int lcnt;
  __shared__ float wz[NT_A / 64];

  if (tid == 0) lcnt = 0;
  __syncthreads();

  const float4* p4 = (const float4*)(logits + (size_t)row * V) + seg * SEG4;
  const int ebase = seg * SEGLEN;
  const float T = 6.0f;  // 64th-largest logit ~6.58; ~173/row expected above 6.0
  const float L2E = 1.44269504088896340736f;
  const float NB  = -16.0f * 1.44269504088896340736f;
  float zs0 = 0.0f, zs1 = 0.0f;

#define PROCV(vv, ii)                                                          \
  {                                                                            \
    float4 v = (vv);                                                           \
    zs0 += __builtin_amdgcn_exp2f(__builtin_fmaf(v.x, L2E, NB));               \
    zs1 += __builtin_amdgcn_exp2f(__builtin_fmaf(v.y, L2E, NB));               \
    zs0 += __builtin_amdgcn_exp2f(__builtin_fmaf(v.z, L2E, NB));               \
    zs1 += __builtin_amdgcn_exp2f(__builtin_fmaf(v.w, L2E, NB));               \
    int eb = ebase + (ii) * 4;                                                 \
    if (v.x > T) { int pos = atomicAdd(&lcnt, 1); if (pos < CAPSEG) lcand[pos] = ((u64)fkey(v.x) << 32) | (u64)(unsigned)(~(unsigned)(eb + 0)); } \
    if (v.y > T) { int pos = atomicAdd(&lcnt, 1); if (pos < CAPSEG) lcand[pos] = ((u64)fkey(v.y) << 32) | (u64)(unsigned)(~(unsigned)(eb + 1)); } \
    if (v.z > T) { int pos = atomicAdd(&lcnt, 1); if (pos < CAPSEG) lcand[pos] = ((u64)fkey(v.z) << 32) | (u64)(unsigned)(~(unsigned)(eb + 2)); } \
    if (v.w > T) { int pos = atomicAdd(&lcnt, 1); if (pos < CAPSEG) lcand[pos] = ((u64)fkey(v.w) << 32) | (u64)(unsigned)(~(unsigned)(eb + 3)); } \
  }

  {
    int i = tid;
    for (; i + NT_A < SEG4; i += 2 * NT_A) {
      float4 a = p4[i];
      float4 c = p4[i + NT_A];
      PROCV(a, i);
      PROCV(c, i + NT_A);
    }
    if (i < SEG4) {
      float4 a = p4[i];
      PROCV(a, i);
    }
  }
#undef PROCV

  float s = zs0 + zs1;
#pragma unroll
  for (int off = 32; off > 0; off >>= 1) s += __shfl_down(s, off);
  if ((tid & 63) == 0) wz[tid >> 6] = s;
  __syncthreads();

  int n = lcnt;  // post-barrier: uniform
  int nc = n < CAPSEG ? n : CAPSEG;
  u64* dst = g_cand + (size_t)bid * CAPSEG;
  for (int i = tid; i < nc; i += NT_A) dst[i] = lcand[i];
  if (tid == 0) {
    float z = 0.0f;
    for (int w = 0; w < NT_A / 64; ++w) z += wz[w];
    g_z[bid] = z;
    g_cnt[bid] = n;  // actual count (may exceed CAPSEG => overflow signal)
  }
}

// ---------------- Kernel B: per-row gather + top-64 + sample -----------------
extern "C" __global__ void __launch_bounds__(NT_B)
sample_row_kernel(const float* __restrict__ logits,
                  const int* __restrict__ kin, const float* __restrict__ pin,
                  int* __restrict__ out,
                  const int* __restrict__ g_cnt, const float* __restrict__ g_z,
                  const u64* __restrict__ g_cand) {
  const int row = blockIdx.x;
  const int tid = threadIdx.x;

  __shared__ u64 cand[CAPB];
  __shared__ u64 topkeys[64];
  __shared__ float sh_sp[64];
  __shared__ float sh_g[64];
  __shared__ int sh_idx[64];
  __shared__ int shCnt[SEGS], shOff[SEGS];
  __shared__ float shZ;
  __shared__ int shN, shSlow, scnt;

  if (tid < SEGS) shCnt[tid] = g_cnt[row * SEGS + tid];
  __syncthreads();
  if (tid == 0) {
    int off = 0, ovf = 0;
    float z = 0.0f;
    for (int s = 0; s < SEGS; ++s) {
      shOff[s] = off;
      int c = shCnt[s];
      if (c > CAPSEG) ovf = 1;
      off += (c < CAPSEG ? c : CAPSEG);
      z += g_z[row * SEGS + s];
    }
    shN = off;
    shZ = z;
    shSlow = (ovf || off < 64) ? 1 : 0;
  }
  __syncthreads();

  int N;
  if (!shSlow) {
    // fast path: gather per-segment candidate slices into LDS
    for (int s = 0; s < SEGS; ++s) {
      int c = shCnt[s];
      c = c < CAPSEG ? c : CAPSEG;
      const u64* src = g_cand + (size_t)(row * SEGS + s) * CAPSEG;
      int off = shOff[s];
      for (int i = tid; i < c; i += NT_B) cand[off + i] = src[i];
    }
    N = shN;
  } else {
    // slow path (correctness guard, ~never taken): full-row rescan w/ adaptive T
    const float4* p4 = (const float4*)(logits + (size_t)row * V);
    float T = 6.0f;
    int attempts = 0;
    while (true) {
      if (tid == 0) scnt = 0;
      __syncthreads();
      for (int i = tid; i < V / 4; i += NT_B) {
        float4 v = p4[i];
        int eb = i * 4;
        if (v.x > T) { int pos = atomicAdd(&scnt, 1); if (pos < CAPB) cand[pos] = ((u64)fkey(v.x) << 32) | (u64)(unsigned)(~(unsigned)(eb + 0)); }
        if (v.y > T) { int pos = atomicAdd(&scnt, 1); if (pos < CAPB) cand[pos] = ((u64)fkey(v.y) << 32) | (u64)(unsigned)(~(unsigned)(eb + 1)); }
        if (v.z > T) { int pos = atomicAdd(&scnt, 1); if (pos < CAPB) cand[pos] = ((u64)fkey(v.z) << 32) | (u64)(unsigned)(~(unsigned)(eb + 2)); }
        if (v.w > T) { int pos = atomicAdd(&scnt, 1); if (pos < CAPB) cand[pos] = ((u64)fkey(v.w) << 32) | (u64)(unsigned)(~(unsigned)(eb + 3)); }
      }
      __syncthreads();
      int n = scnt;
      if ((n >= 64 && n <= CAPB) || attempts >= 24) break;
      T = (n < 64) ? (T - 2.0f) : (T + 1.0f);
      ++attempts;
      __syncthreads();
    }
    N = scnt < CAPB ? scnt : CAPB;
  }
  __syncthreads();

  // exact top-64 by (value desc, index asc) via rank counting (keys unique)
  for (int i = tid; i < N; i += NT_B) {
    u64 ki = cand[i];
    int rank = 0;
    for (int j = 0; j < N; ++j) rank += (cand[j] > ki) ? 1 : 0;
    if (rank < 64) topkeys[rank] = ki;
  }
  __syncthreads();

  int M = N < 64 ? N : 64;

  // per-rank prob + gumbel (rank r uses flat index row*V + r)
  if (tid < M) {
    u64 key = topkeys[tid];
    float v = fkey_inv((unsigned)(key >> 32));
    sh_sp[tid] = expf(v - T0) / shZ;
    sh_idx[tid] = (int)(~((unsigned)(key & 0xFFFFFFFFull)));
    sh_g[tid] = gumbel_at((unsigned)((size_t)row * V + tid));
  }
  __syncthreads();

  // serial epilogue replicating reference float ops [byte-identical to R4/R5]
  if (tid == 0) {
    int kk = kin[row];
    float pp = pin[row];
    float c = 0.0f, S = 0.0f;
    u64 keepmask = 0ull;
    for (int r = 0; r < M; ++r) {
      float sp = sh_sp[r];
      c += sp;
      if (r < kk && (c - sp) < pp) {
        S += sp;
        keepmask |= (1ull << r);
      }
    }
    float best = -1e38f;
    int besti = sh_idx[0];
    for (int r = 0; r < M; ++r) {
      if (!(keepmask & (1ull << r))) continue;
      float lp = logf(fmaxf(sh_sp[r] / S, 1e-38f));
      float y = lp + sh_g[r];
      if (y > best) { best = y; besti = sh_idx[r]; }
    }
    out[row] = besti;
  }
}

extern "C" void kernel_launch(void* const* d_in, const int* in_sizes, int n_in,
                              void* d_out, int out_size, void* d_ws, size_t ws_size,
                              hipStream_t stream) {
  const float* logits = (const float*)d_in[0];
  const int* k = (const int*)d_in[1];
  const float* p = (const float*)d_in[2];
  int* out = (int*)d_out;
  (void)in_sizes; (void)n_in; (void)out_size; (void)ws_size;

  // workspace layout
  char* ws = (char*)d_ws;
  int* g_cnt = (int*)ws;                                    // 256*8 ints   (8 KB)
  float* g_z = (float*)(ws + 16384);                        // 256*8 floats (8 KB)
  u64* g_cand = (u64*)(ws + 32768);                         // 256*8*512 u64 (8 MB)

  scan_seg_kernel<<<BROWS * SEGS, NT_A, 0, stream>>>(logits, g_cnt, g_z, g_cand);
  sample_row_kernel<<<BROWS, NT_B, 0, stream>>>(logits, k, p, out, g_cnt, g_z, g_cand);
}

// Round 7
// 202.917 us; speedup vs baseline: 1.0539x; 1.0539x over previous
//
#include <hip/hip_runtime.h>
#include <stdint.h>

#define V 128000
#define V4 (V / 4)
#define BROWS 256
#define CAP 2048
#define NTHREADS 1024
#define T0 16.0f

__device__ __forceinline__ unsigned rotl32(unsigned x, int d) {
  return (x << d) | (x >> (32 - d));
}

// JAX threefry2x32, key (0, 42) == jax.random.key(42).
// PARTITIONABLE path (default since JAX 0.4.30): counter = (0, i);
// 32-bit draw = XOR-fold of the two output words.  [verified: R4/R5/R6 passed]
__device__ __forceinline__ uint2 threefry2x32(unsigned x0, unsigned x1) {
  const unsigned k0 = 0u, k1 = 42u;
  const unsigned k2 = k0 ^ k1 ^ 0x1BD11BDAu;
  x0 += k0; x1 += k1;
#define TF_RND(r) { x0 += x1; x1 = rotl32(x1, r); x1 ^= x0; }
  TF_RND(13) TF_RND(15) TF_RND(26) TF_RND(6)
  x0 += k1; x1 += k2 + 1u;
  TF_RND(17) TF_RND(29) TF_RND(16) TF_RND(24)
  x0 += k2; x1 += k0 + 2u;
  TF_RND(13) TF_RND(15) TF_RND(26) TF_RND(6)
  x0 += k0; x1 += k1 + 3u;
  TF_RND(17) TF_RND(29) TF_RND(16) TF_RND(24)
  x0 += k1; x1 += k2 + 4u;
  TF_RND(13) TF_RND(15) TF_RND(26) TF_RND(6)
  x0 += k2; x1 += k0 + 5u;
#undef TF_RND
  return make_uint2(x0, x1);
}

__device__ __forceinline__ float gumbel_at(unsigned flat) {
  uint2 r = threefry2x32(0u, flat);
  unsigned bits = r.x ^ r.y;  // XOR fold
  float f = __uint_as_float((bits >> 9) | 0x3F800000u) - 1.0f;
  const float TINY = 1.17549435e-38f;
  float u = fmaxf(TINY, f + TINY);
  return -logf(-logf(u));
}

// monotone float -> uint mapping (total order, sign-robust)
__device__ __forceinline__ unsigned fkey(float v) {
  unsigned u = __float_as_uint(v);
  return (u & 0x80000000u) ? ~u : (u | 0x80000000u);
}
__device__ __forceinline__ float fkey_inv(unsigned u) {
  unsigned r = (u & 0x80000000u) ? (u & 0x7FFFFFFFu) : ~u;
  return __uint_as_float(r);
}

extern "C" __global__ void __launch_bounds__(NTHREADS)
topk_topp_sample_kernel(const float* __restrict__ logits,
                        const int* __restrict__ kin,
                        const float* __restrict__ pin,
                        int* __restrict__ out) {
  const int b = blockIdx.x;
  const int tid = threadIdx.x;

  __shared__ unsigned long long cand[CAP];
  __shared__ unsigned long long topkeys[64];
  __shared__ float zpart[NTHREADS / 64];
  __shared__ float sh_sp[64];
  __shared__ float sh_g[64];
  __shared__ int sh_idx[64];
  __shared__ int cnt;
  __shared__ float shZ;

  const float4* row4 = (const float4*)(logits + (size_t)b * V);
  float T = 6.0f;  // 64th largest logit ~6.58; ~173 expected above 6.0

  if (tid == 0) cnt = 0;
  __syncthreads();

  // ---- streaming pass: Z via native v_exp_f32 (Z needs only ~3 digits:
  // it cancels in log(sp/S); top-p mask has >=2.5x slack) + candidate collect.
  const float L2E = 1.44269504088896340736f;
  const float NB  = -16.0f * 1.44269504088896340736f;
  float zs0 = 0.0f, zs1 = 0.0f;

#define PROCV(vv, ii)                                                          \
  {                                                                            \
    float4 v = (vv);                                                           \
    zs0 += __builtin_amdgcn_exp2f(__builtin_fmaf(v.x, L2E, NB));               \
    zs1 += __builtin_amdgcn_exp2f(__builtin_fmaf(v.y, L2E, NB));               \
    zs0 += __builtin_amdgcn_exp2f(__builtin_fmaf(v.z, L2E, NB));               \
    zs1 += __builtin_amdgcn_exp2f(__builtin_fmaf(v.w, L2E, NB));               \
    int base = (ii) * 4;                                                       \
    if (v.x > T) { int pos = atomicAdd(&cnt, 1); if (pos < CAP) cand[pos] = ((unsigned long long)fkey(v.x) << 32) | (unsigned long long)(unsigned)(~(unsigned)(base + 0)); } \
    if (v.y > T) { int pos = atomicAdd(&cnt, 1); if (pos < CAP) cand[pos] = ((unsigned long long)fkey(v.y) << 32) | (unsigned long long)(unsigned)(~(unsigned)(base + 1)); } \
    if (v.z > T) { int pos = atomicAdd(&cnt, 1); if (pos < CAP) cand[pos] = ((unsigned long long)fkey(v.z) << 32) | (unsigned long long)(unsigned)(~(unsigned)(base + 2)); } \
    if (v.w > T) { int pos = atomicAdd(&cnt, 1); if (pos < CAP) cand[pos] = ((unsigned long long)fkey(v.w) << 32) | (unsigned long long)(unsigned)(~(unsigned)(base + 3)); } \
  }

  {
    int i = tid;
    for (; i + NTHREADS < V4; i += 2 * NTHREADS) {
      float4 a = row4[i];               // both loads issued before first use
      float4 c = row4[i + NTHREADS];
      PROCV(a, i);
      PROCV(c, i + NTHREADS);
    }
    if (i < V4) {
      float4 a = row4[i];
      PROCV(a, i);
    }
  }
  float s = zs0 + zs1;

  // block-reduce Z
#pragma unroll
  for (int off = 32; off > 0; off >>= 1) s += __shfl_down(s, off);
  if ((tid & 63) == 0) zpart[tid >> 6] = s;
  __syncthreads();
  if (tid == 0) {
    float z = 0.0f;
    for (int w = 0; w < NTHREADS / 64; ++w) z += zpart[w];
    shZ = z;
  }
  __syncthreads();

  // ---- fallback: adjust threshold if candidate count out of [64, CAP]
  int attempts = 0;
  while (true) {
    int n = cnt;  // uniform across block: read after barrier
    if ((n >= 64 && n <= CAP) || attempts >= 24) break;
    T = (n < 64) ? (T - 2.0f) : (T + 1.0f);
    ++attempts;
    __syncthreads();
    if (tid == 0) cnt = 0;
    __syncthreads();
    for (int i = tid; i < V4; i += NTHREADS) {
      float4 v = row4[i];
      int base = i * 4;
      if (v.x > T) { int pos = atomicAdd(&cnt, 1); if (pos < CAP) cand[pos] = ((unsigned long long)fkey(v.x) << 32) | (unsigned long long)(unsigned)(~(unsigned)(base + 0)); }
      if (v.y > T) { int pos = atomicAdd(&cnt, 1); if (pos < CAP) cand[pos] = ((unsigned long long)fkey(v.y) << 32) | (unsigned long long)(unsigned)(~(unsigned)(base + 1)); }
      if (v.z > T) { int pos = atomicAdd(&cnt, 1); if (pos < CAP) cand[pos] = ((unsigned long long)fkey(v.z) << 32) | (unsigned long long)(unsigned)(~(unsigned)(base + 2)); }
      if (v.w > T) { int pos = atomicAdd(&cnt, 1); if (pos < CAP) cand[pos] = ((unsigned long long)fkey(v.w) << 32) | (unsigned long long)(unsigned)(~(unsigned)(base + 3)); }
    }
    __syncthreads();
  }

  int N = cnt < CAP ? cnt : CAP;

  // ---- exact top-64 by (value desc, index asc) via rank counting.
  for (int i = tid; i < N; i += NTHREADS) {
    unsigned long long ki = cand[i];
    int rank = 0;
    for (int j = 0; j < N; ++j) rank += (cand[j] > ki) ? 1 : 0;
    if (rank < 64) topkeys[rank] = ki;
  }
  __syncthreads();

  int M = N < 64 ? N : 64;

  // ---- per-rank prob + gumbel (rank r uses flat index b*V + r)
  if (tid < M) {
    unsigned long long key = topkeys[tid];
    float v = fkey_inv((unsigned)(key >> 32));
    sh_sp[tid] = expf(v - T0) / shZ;
    sh_idx[tid] = (int)(~((unsigned)(key & 0xFFFFFFFFull)));
    sh_g[tid] = gumbel_at((unsigned)((size_t)b * V + tid));
  }
  __syncthreads();

  // ---- serial epilogue replicating reference float ops
  if (tid == 0) {
    int kk = kin[b];
    float pp = pin[b];
    float c = 0.0f, S = 0.0f;
    unsigned long long keepmask = 0ull;
    for (int r = 0; r < M; ++r) {
      float sp = sh_sp[r];
      c += sp;                         // inclusive cumsum, sequential fp32
      if (r < kk && (c - sp) < pp) {   // reference: (csum - sp) < p
        S += sp;
        keepmask |= (1ull << r);
      }
    }
    float best = -1e38f;
    int besti = sh_idx[0];
    for (int r = 0; r < M; ++r) {
      if (!(keepmask & (1ull << r))) continue;
      float lp = logf(fmaxf(sh_sp[r] / S, 1e-38f));
      float y = lp + sh_g[r];
      if (y > best) { best = y; besti = sh_idx[r]; }  // strict > = first occurrence
    }
    out[b] = besti;
  }
}

extern "C" void kernel_launch(void* const* d_in, const int* in_sizes, int n_in,
                              void* d_out, int out_size, void* d_ws, size_t ws_size,
                              hipStream_t stream) {
  const float* logits = (const float*)d_in[0];
  const int* k = (const int*)d_in[1];
  const float* p = (const float*)d_in[2];
  int* out = (int*)d_out;
  (void)in_sizes; (void)n_in; (void)out_size; (void)d_ws; (void)ws_size;
  topk_topp_sample_kernel<<<BROWS, NTHREADS, 0, stream>>>(logits, k, p, out);
}